// Round 1
// baseline (64039.221 us; speedup 1.0000x reference)
//
#include <hip/hip_runtime.h>
#include <stdint.h>

#define VV 1000
#define EE 1024
#define DD 512
#define AA 512
#define TT 128
#define BB 128
#define PP 196
#define SS 256

typedef unsigned short ushort_t;
typedef __attribute__((ext_vector_type(8))) short short8;
typedef __attribute__((ext_vector_type(4))) float floatx4;
typedef __attribute__((ext_vector_type(4))) unsigned short ushort4_t;
typedef __attribute__((ext_vector_type(8))) unsigned short ushort8_t;

__device__ __forceinline__ float bf2f(unsigned short h) {
    return __uint_as_float(((unsigned int)h) << 16);
}
__device__ __forceinline__ unsigned short f2bf(float x) {
    unsigned int u = __float_as_uint(x);
    unsigned int r = (u + 0x7fffu + ((u >> 16) & 1u)) >> 16;
    return (unsigned short)r;
}
__device__ __forceinline__ float fast_rcp(float x) { return __builtin_amdgcn_rcpf(x); }
__device__ __forceinline__ float sigmoidf_(float x) { return fast_rcp(1.f + __expf(-x)); }
__device__ __forceinline__ float tanhf_(float x) {
    // 1 - 2/(e^{2x}+1): saturates correctly at +/-inf without NaN; rcp err ~1e-6
    float e = __expf(2.f * x);
    return 1.f - 2.f * fast_rcp(e + 1.f);
}

template <int NKS>
__device__ __forceinline__ floatx4 mmK(const short8* __restrict__ ap,
                                       const short8* __restrict__ bp, floatx4 acc) {
#pragma unroll
    for (int ks = 0; ks < NKS; ++ks)
        acc = __builtin_amdgcn_mfma_f32_16x16x32_bf16(ap[ks * 4], bp[ks * 4], acc, 0, 0, 0);
    return acc;
}

// ---------------- one-time prep kernels ----------------

__global__ void cvt_kernel(const float* __restrict__ src, ushort_t* __restrict__ dst, int n) {
    int i = blockIdx.x * 256 + threadIdx.x;
    if (i < n) dst[i] = f2bf(src[i]);
}

__global__ void zero_kernel(int* __restrict__ p, int n) {
    int i = blockIdx.x * 256 + threadIdx.x;
    if (i < n) p[i] = 0;
}

__global__ void mean_kernel(const float* __restrict__ feat, float* __restrict__ meanv) {
    int idx = blockIdx.x * 256 + threadIdx.x;  // 131072 = 128*1024
    int b = idx >> 10;
    int e = idx & 1023;
    const float* p = feat + (size_t)b * PP * 1024 + e;
    float s = 0.f;
    for (int pp = 0; pp < PP; ++pp) s += p[(size_t)pp * 1024];
    meanv[idx] = s * (1.f / 196.f);
}

__global__ __launch_bounds__(256) void init_kernel(
    const float* __restrict__ meanv, const float* __restrict__ Wh0, const float* __restrict__ bh0,
    const float* __restrict__ Wc0, const float* __restrict__ bc0,
    float* __restrict__ c1, float* __restrict__ c2,
    ushort_t* __restrict__ h1b, ushort_t* __restrict__ h2b) {
    int b = blockIdx.x, t = threadIdx.x;
    __shared__ float ml[1024];
    for (int i = t; i < 1024; i += 256) ml[i] = meanv[b * 1024 + i];
    __syncthreads();
    for (int d = t; d < 512; d += 256) {
        const float4* wh = (const float4*)(Wh0 + (size_t)d * 1024);
        const float4* wc = (const float4*)(Wc0 + (size_t)d * 1024);
        float ah = bh0[d], ac = bc0[d];
        #pragma unroll 4
        for (int j = 0; j < 256; ++j) {
            float4 w = wh[j];
            ah += w.x * ml[4 * j] + w.y * ml[4 * j + 1] + w.z * ml[4 * j + 2] + w.w * ml[4 * j + 3];
        }
        #pragma unroll 4
        for (int j = 0; j < 256; ++j) {
            float4 w = wc[j];
            ac += w.x * ml[4 * j] + w.y * ml[4 * j + 1] + w.z * ml[4 * j + 2] + w.w * ml[4 * j + 3];
        }
        c1[b * 512 + d] = ac;
        c2[b * 512 + d] = ac;
        ushort_t hb = f2bf(ah);
        h1b[b * 512 + d] = hb;
        h2b[b * 512 + d] = hb;
    }
}

// enc_t = features @ Wenc^T + benc, stored bf16.  M=25088, N=512, K=1024.
__global__ __launch_bounds__(256) void enc_gemm(
    const ushort_t* __restrict__ feat_bf, const ushort_t* __restrict__ wenc_bf,
    const float* __restrict__ benc, ushort_t* __restrict__ enc_bf) {
    const int t = threadIdx.x, blk = blockIdx.x;
    const int bm = (blk % 392) * 64, bn = (blk / 392) * 64;
    const int lane = t & 63, wv = t >> 6;
    const int n = lane & 15, q = lane >> 4;
    const int arow = bm + wv * 16 + n;
    const short8* ap = (const short8*)(feat_bf + (size_t)arow * 1024 + q * 8);
    const short8* bp0 = (const short8*)(wenc_bf + (size_t)(bn + 0 * 16 + n) * 1024 + q * 8);
    const short8* bp1 = (const short8*)(wenc_bf + (size_t)(bn + 1 * 16 + n) * 1024 + q * 8);
    const short8* bp2 = (const short8*)(wenc_bf + (size_t)(bn + 2 * 16 + n) * 1024 + q * 8);
    const short8* bp3 = (const short8*)(wenc_bf + (size_t)(bn + 3 * 16 + n) * 1024 + q * 8);
    floatx4 acc0 = {0.f, 0.f, 0.f, 0.f}, acc1 = acc0, acc2 = acc0, acc3 = acc0;
    for (int ks = 0; ks < 32; ++ks) {
        short8 a8 = ap[ks * 4];
        acc0 = __builtin_amdgcn_mfma_f32_16x16x32_bf16(a8, bp0[ks * 4], acc0, 0, 0, 0);
        acc1 = __builtin_amdgcn_mfma_f32_16x16x32_bf16(a8, bp1[ks * 4], acc1, 0, 0, 0);
        acc2 = __builtin_amdgcn_mfma_f32_16x16x32_bf16(a8, bp2[ks * 4], acc2, 0, 0, 0);
        acc3 = __builtin_amdgcn_mfma_f32_16x16x32_bf16(a8, bp3[ks * 4], acc3, 0, 0, 0);
    }
    #pragma unroll
    for (int r = 0; r < 4; ++r) {
        int m = bm + wv * 16 + q * 4 + r;
        int a0 = bn + n;
        enc_bf[(size_t)m * 512 + a0] = f2bf(acc0[r] + benc[a0]);
        enc_bf[(size_t)m * 512 + a0 + 16] = f2bf(acc1[r] + benc[a0 + 16]);
        enc_bf[(size_t)m * 512 + a0 + 32] = f2bf(acc2[r] + benc[a0 + 32]);
        enc_bf[(size_t)m * 512 + a0 + 48] = f2bf(acc3[r] + benc[a0 + 48]);
    }
}

// ---------------- persistent decode loop ----------------
//
// 256 WGs x 256 threads (grid == CU count -> all WGs resident; no deadlock).
// Hierarchical monotonic grid barrier: 8 group counters (32 WGs each, separate
// cache lines) -> root counter -> generation flag. Counters never reset
// (targets are 32*k / 8*k), so there are no reset races. AGENT-scope atomics +
// __threadfence give cross-XCD visibility of plain stores.
__device__ __forceinline__ void gbar(int* __restrict__ bar, int k) {
    __syncthreads();
    if (threadIdx.x == 0) {
        __threadfence();
        int* grp = bar + (blockIdx.x >> 5) * 32;
        int old = __hip_atomic_fetch_add(grp, 1, __ATOMIC_ACQ_REL, __HIP_MEMORY_SCOPE_AGENT);
        if (old + 1 == 32 * k) {
            int r = __hip_atomic_fetch_add(bar + 256, 1, __ATOMIC_ACQ_REL, __HIP_MEMORY_SCOPE_AGENT);
            if (r + 1 == 8 * k) {
                __hip_atomic_store(bar + 288, k, __ATOMIC_RELEASE, __HIP_MEMORY_SCOPE_AGENT);
            }
        }
        while (__hip_atomic_load(bar + 288, __ATOMIC_ACQUIRE, __HIP_MEMORY_SCOPE_AGENT) < k) {
            __builtin_amdgcn_s_sleep(2);
        }
        __threadfence();
    }
    __syncthreads();
}

// vocab projection: preds[s-1] = h2 @ Wf^T + bf; 126 WGs x [64 rows x 16 cols], K=512
__device__ __forceinline__ void preds_tile(int w2, int s, const ushort_t* __restrict__ h2cur,
                                           const ushort_t* __restrict__ wf_bf,
                                           const float* __restrict__ bfv,
                                           float* __restrict__ out, int wv, int n, int q) {
    const int v0 = (w2 >> 1) * 16;
    const int m0 = (w2 & 1) * 64 + wv * 16;
    const int vrow = v0 + n;
    const int vc = vrow < VV ? vrow : VV - 1;
    const short8* bp = (const short8*)(wf_bf + (size_t)vc * 512 + q * 8);
    const short8* ap = (const short8*)(h2cur + (size_t)(m0 + n) * 512 + q * 8);
    floatx4 acc0 = {0.f, 0.f, 0.f, 0.f}, acc1 = acc0;
    acc0 = mmK<8>(ap, bp, acc0);
    acc1 = mmK<8>(ap + 32, bp + 32, acc1);
    acc0 += acc1;
    if (vrow < VV) {
        const float cb = bfv[vrow];
        const size_t so = (size_t)(s - 1) * 1000 + vrow;
        #pragma unroll
        for (int r = 0; r < 4; ++r)
            out[(size_t)(m0 + q * 4 + r) * 256000 + so] = acc0[r] + cb;
    }
}

// one LSTM layer phase: gates = A1 @ Wih^T + A2 @ Whh^T (+biases); c in place; h out bf16.
// 256 WGs: rowhalf = wg>>7 (64 batches), d-block = (wg&127)*4; 16 interleaved gate cols.
__device__ __forceinline__ void lstm_phase(
    int wg, int t, int wv, int n, int q,
    const ushort_t* __restrict__ A1, int k1, const ushort_t* __restrict__ Wih,
    const ushort_t* __restrict__ A2v, const ushort_t* __restrict__ Whh,
    const float* __restrict__ bih, const float* __restrict__ bhh,
    float* __restrict__ cst, ushort_t* __restrict__ hout, float (*glds)[17]) {
    const int rh = wg >> 7, d0 = (wg & 127) * 4;
    const int col = (n >> 2) * 512 + d0 + (n & 3);  // gate-interleaved column
    const int m0 = rh * 64 + wv * 16;
    floatx4 acc0 = {0.f, 0.f, 0.f, 0.f}, acc1 = acc0;
    {
        const short8* bp = (const short8*)(Wih + (size_t)col * k1 + q * 8);
        const short8* ap = (const short8*)(A1 + (size_t)(m0 + n) * k1 + q * 8);
        if (k1 == 1152) {  // call sites pass literals -> branch folds after inlining
            acc0 = mmK<18>(ap, bp, acc0);
            acc1 = mmK<18>(ap + 72, bp + 72, acc1);
        } else {
            acc0 = mmK<8>(ap, bp, acc0);
            acc1 = mmK<8>(ap + 32, bp + 32, acc1);
        }
    }
    {
        const short8* bp = (const short8*)(Whh + (size_t)col * 512 + q * 8);
        const short8* ap = (const short8*)(A2v + (size_t)(m0 + n) * 512 + q * 8);
        acc0 = mmK<8>(ap, bp, acc0);
        acc1 = mmK<8>(ap + 32, bp + 32, acc1);
    }
    acc0 += acc1;
    #pragma unroll
    for (int r = 0; r < 4; ++r) glds[wv * 16 + q * 4 + r][n] = acc0[r];
    __syncthreads();
    const int bl = t >> 2, dj = t & 3;
    const int d = d0 + dj;
    const int b = rh * 64 + bl;
    float gi = glds[bl][dj] + bih[d] + bhh[d];
    float gf = glds[bl][4 + dj] + bih[512 + d] + bhh[512 + d];
    float gg = glds[bl][8 + dj] + bih[1024 + d] + bhh[1024 + d];
    float go = glds[bl][12 + dj] + bih[1536 + d] + bhh[1536 + d];
    float co = cst[b * 512 + d];
    float cn = sigmoidf_(gf) * co + sigmoidf_(gi) * tanhf_(gg);
    float hn = sigmoidf_(go) * tanhf_(cn);
    cst[b * 512 + d] = cn;
    hout[b * 512 + d] = f2bf(hn);
}

__global__ __launch_bounds__(256, 1) void decode_loop(
    const ushort_t* __restrict__ enc_bf, const ushort_t* __restrict__ feat_bf,
    const ushort_t* __restrict__ wdec_bf, const ushort_t* __restrict__ wf_bf,
    const ushort_t* __restrict__ emb_bf,
    const ushort_t* __restrict__ w1ih_bf, const ushort_t* __restrict__ w1hh_bf,
    const ushort_t* __restrict__ w2ih_bf, const ushort_t* __restrict__ w2hh_bf,
    const int* __restrict__ latexes,
    const float* __restrict__ wattn, const float* __restrict__ battn,
    const float* __restrict__ bdec, const float* __restrict__ bfv,
    const float* __restrict__ b1ih, const float* __restrict__ b1hh,
    const float* __restrict__ b2ih, const float* __restrict__ b2hh,
    float* __restrict__ c1, float* __restrict__ c2,
    ushort_t* __restrict__ h1b0, ushort_t* __restrict__ h1b1,
    ushort_t* __restrict__ h2b0, ushort_t* __restrict__ h2b1,
    ushort_t* __restrict__ x1_bf, float* __restrict__ decb,
    float* __restrict__ out, int* __restrict__ bar) {
    const int wg = blockIdx.x, t = threadIdx.x;
    const int lane = t & 63, wv = t >> 6;
    const int n = lane & 15, q = lane >> 4;

    __shared__ float wa_lds[512];
    __shared__ float dec_lds[512];
    __shared__ float red[256];
    __shared__ float attn_lds[200];
    __shared__ float alpha_lds[200];
    __shared__ float glds[64][17];

    for (int i = t; i < 512; i += 256) wa_lds[i] = wattn[i];  // first use is after a gbar

    int bc = 0;
    for (int s = 0;; ++s) {
        const ushort_t* h1cur = (s & 1) ? h1b1 : h1b0;
        const ushort_t* h2cur = (s & 1) ? h2b1 : h2b0;
        ushort_t* h1nxt = (s & 1) ? h1b0 : h1b1;
        ushort_t* h2nxt = (s & 1) ? h2b0 : h2b1;

        // ---- Phase A1: dec_t = h2 @ Wdec^T + bdec  (64 WGs x [64 x 16], K=512) ----
        if (wg < 64 && s < SS) {
            const int n0 = (wg >> 1) * 16;
            const int m0 = (wg & 1) * 64 + wv * 16;
            const short8* ap = (const short8*)(h2cur + (size_t)(m0 + n) * 512 + q * 8);
            const short8* bp = (const short8*)(wdec_bf + (size_t)(n0 + n) * 512 + q * 8);
            floatx4 acc0 = {0.f, 0.f, 0.f, 0.f}, acc1 = acc0;
            acc0 = mmK<8>(ap, bp, acc0);
            acc1 = mmK<8>(ap + 32, bp + 32, acc1);
            acc0 += acc1;
            const float cb = bdec[n0 + n];
            #pragma unroll
            for (int r = 0; r < 4; ++r)
                decb[(size_t)(m0 + q * 4 + r) * 512 + n0 + n] = acc0[r] + cb;
        }
        if (s == SS) {
            // final vocab projection preds[SS-1] (h2 final lives in h2b0 = h2cur here)
            if (wg >= 128 && wg < 254) preds_tile(wg - 128, SS, h2cur, wf_bf, bfv, out, wv, n, q);
            break;  // all WGs break together; no trailing barrier needed
        }
        gbar(bar, ++bc);

        // ---- Phase A2: attention (WG 0..127) || preds[s-1] (WG 128..253) ----
        if (wg < BB) {
            const int b = wg;
            if (t < TT) {
                int tok = latexes[b * 257 + s];
                x1_bf[(size_t)b * 1152 + t] = emb_bf[tok * TT + t];
            }
            for (int i = t; i < 512; i += 256) dec_lds[i] = decb[b * 512 + i];
            __syncthreads();
            const float ba = battn[0];
            // logits: attn[p] = wa . tanh(enc[b,p,:] + dec) + ba
            for (int p = wv; p < PP; p += 4) {
                const ushort8_t ev =
                    *(const ushort8_t*)(enc_bf + ((size_t)(b * PP + p)) * 512 + lane * 8);
                float acc = 0.f;
                #pragma unroll
                for (int u = 0; u < 8; ++u) {
                    float x = bf2f(ev[u]) + dec_lds[lane * 8 + u];
                    acc += wa_lds[lane * 8 + u] * tanhf_(x);
                }
                #pragma unroll
                for (int off = 32; off > 0; off >>= 1) acc += __shfl_xor(acc, off, 64);
                if (lane == 0) attn_lds[p] = acc + ba;
            }
            __syncthreads();
            // softmax over 196
            float logit = (t < PP) ? attn_lds[t] : -1e30f;
            red[t] = logit;
            __syncthreads();
            for (int st = 128; st > 0; st >>= 1) {
                if (t < st) red[t] = fmaxf(red[t], red[t + st]);
                __syncthreads();
            }
            float mx = red[0];
            __syncthreads();
            float e = (t < PP) ? __expf(logit - mx) : 0.f;
            red[t] = e;
            __syncthreads();
            for (int st = 128; st > 0; st >>= 1) {
                if (t < st) red[t] += red[t + st];
                __syncthreads();
            }
            float inv = 1.f / red[0];
            float a = e * inv;
            if (t < PP) {
                alpha_lds[t] = a;
                out[(size_t)32768000 + (size_t)b * 50176 + (size_t)s * 196 + t] = a;
            }
            __syncthreads();
            // awe[b,e] = sum_p alpha[p]*feat[b,p,e]; x1 = [emb | awe] bf16
            float a0 = 0.f, a1 = 0.f, a2 = 0.f, a3 = 0.f;
            const int e0 = t * 4;
            for (int p = 0; p < PP; ++p) {
                float av = alpha_lds[p];
                ushort4_t f4 = *(const ushort4_t*)(feat_bf + ((size_t)(b * PP + p)) * 1024 + e0);
                a0 += av * bf2f(f4[0]);
                a1 += av * bf2f(f4[1]);
                a2 += av * bf2f(f4[2]);
                a3 += av * bf2f(f4[3]);
            }
            ushort4_t o4;
            o4[0] = f2bf(a0); o4[1] = f2bf(a1); o4[2] = f2bf(a2); o4[3] = f2bf(a3);
            *(ushort4_t*)(x1_bf + (size_t)b * 1152 + TT + e0) = o4;
        } else if (wg >= 128 && wg < 254 && s > 0) {
            preds_tile(wg - 128, s, h2cur, wf_bf, bfv, out, wv, n, q);
        }
        gbar(bar, ++bc);

        // ---- Phase B: lstm1 ----
        lstm_phase(wg, t, wv, n, q, x1_bf, 1152, w1ih_bf, h1cur, w1hh_bf,
                   b1ih, b1hh, c1, h1nxt, glds);
        gbar(bar, ++bc);

        // ---- Phase C: lstm2 ----
        lstm_phase(wg, t, wv, n, q, h1nxt, 512, w2ih_bf, h2cur, w2hh_bf,
                   b2ih, b2hh, c2, h2nxt, glds);
        gbar(bar, ++bc);
    }
}

extern "C" void kernel_launch(void* const* d_in, const int* in_sizes, int n_in,
                              void* d_out, int out_size, void* d_ws, size_t ws_size,
                              hipStream_t stream) {
    const float* features = (const float*)d_in[0];
    const int* latexes = (const int*)d_in[1];
    const float* emb = (const float*)d_in[2];
    const float* Wenc = (const float*)d_in[3];
    const float* benc = (const float*)d_in[4];
    const float* Wdec = (const float*)d_in[5];
    const float* bdec = (const float*)d_in[6];
    const float* Wattn = (const float*)d_in[7];
    const float* battn = (const float*)d_in[8];
    const float* W1ih = (const float*)d_in[9];
    const float* W1hh = (const float*)d_in[10];
    const float* b1ih = (const float*)d_in[11];
    const float* b1hh = (const float*)d_in[12];
    const float* W2ih = (const float*)d_in[13];
    const float* W2hh = (const float*)d_in[14];
    const float* b2ih = (const float*)d_in[15];
    const float* b2hh = (const float*)d_in[16];
    const float* Wh0 = (const float*)d_in[17];
    const float* bh0 = (const float*)d_in[18];
    const float* Wc0 = (const float*)d_in[19];
    const float* bc0 = (const float*)d_in[20];
    const float* Wf = (const float*)d_in[23];
    const float* bfv = (const float*)d_in[24];
    float* out = (float*)d_out;

    char* ws = (char*)d_ws;
    size_t off = 0;
    auto alloc = [&](size_t bytes) {
        void* p = ws + off;
        off += (bytes + 255) & ~(size_t)255;
        return p;
    };
    ushort_t* feat_bf = (ushort_t*)alloc(25690112ull * 2);
    ushort_t* enc_bf = (ushort_t*)alloc(12845056ull * 2);
    ushort_t* w1ih_bf = (ushort_t*)alloc(2359296ull * 2);
    ushort_t* w1hh_bf = (ushort_t*)alloc(1048576ull * 2);
    ushort_t* w2ih_bf = (ushort_t*)alloc(1048576ull * 2);
    ushort_t* w2hh_bf = (ushort_t*)alloc(1048576ull * 2);
    ushort_t* wf_bf = (ushort_t*)alloc(512000ull * 2);
    ushort_t* wdec_bf = (ushort_t*)alloc(262144ull * 2);
    ushort_t* wenc_bf = (ushort_t*)alloc(524288ull * 2);
    ushort_t* emb_bf = (ushort_t*)alloc(128000ull * 2);
    float* meanv = (float*)alloc(131072ull * 4);
    float* c1 = (float*)alloc(65536ull * 4);
    float* c2 = (float*)alloc(65536ull * 4);
    ushort_t* h1b0 = (ushort_t*)alloc(65536ull * 2);
    ushort_t* h1b1 = (ushort_t*)alloc(65536ull * 2);
    ushort_t* h2b0 = (ushort_t*)alloc(65536ull * 2);
    ushort_t* h2b1 = (ushort_t*)alloc(65536ull * 2);
    ushort_t* x1_bf = (ushort_t*)alloc(147456ull * 2);
    float* decb = (float*)alloc(65536ull * 4);
    int* bar = (int*)alloc(512 * sizeof(int));

    auto cv = [&](const float* s, ushort_t* d, int n) {
        cvt_kernel<<<(n + 255) / 256, 256, 0, stream>>>(s, d, n);
    };
    cv(features, feat_bf, 25690112);
    cv(Wenc, wenc_bf, 524288);
    cv(W1ih, w1ih_bf, 2359296);
    cv(W1hh, w1hh_bf, 1048576);
    cv(W2ih, w2ih_bf, 1048576);
    cv(W2hh, w2hh_bf, 1048576);
    cv(Wf, wf_bf, 512000);
    cv(Wdec, wdec_bf, 262144);
    cv(emb, emb_bf, 128000);
    zero_kernel<<<2, 256, 0, stream>>>(bar, 512);
    mean_kernel<<<512, 256, 0, stream>>>(features, meanv);
    init_kernel<<<128, 256, 0, stream>>>(meanv, Wh0, bh0, Wc0, bc0, c1, c2, h1b0, h2b0);
    enc_gemm<<<3136, 256, 0, stream>>>(feat_bf, wenc_bf, benc, enc_bf);

    decode_loop<<<256, 256, 0, stream>>>(
        enc_bf, feat_bf, wdec_bf, wf_bf, emb_bf, w1ih_bf, w1hh_bf, w2ih_bf, w2hh_bf,
        latexes, Wattn, battn, bdec, bfv, b1ih, b1hh, b2ih, b2hh,
        c1, c2, h1b0, h1b1, h2b0, h2b1, x1_bf, decb, out, bar);
}

// Round 3
// 32830.774 us; speedup vs baseline: 1.9506x; 1.9506x over previous
//
#include <hip/hip_runtime.h>
#include <stdint.h>

#define VV 1000
#define EE 1024
#define DD 512
#define AA 512
#define TT 128
#define BB 128
#define PP 196
#define SS 256

typedef unsigned short ushort_t;
typedef unsigned long long ull_t;
typedef __attribute__((ext_vector_type(8))) short short8;
typedef __attribute__((ext_vector_type(4))) float floatx4;
typedef __attribute__((ext_vector_type(4))) unsigned short ushort4_t;
typedef __attribute__((ext_vector_type(8))) unsigned short ushort8_t;
typedef __attribute__((ext_vector_type(2))) unsigned long long ull2;

__device__ __forceinline__ float bf2f(unsigned short h) {
    return __uint_as_float(((unsigned int)h) << 16);
}
__device__ __forceinline__ unsigned short f2bf(float x) {
    unsigned int u = __float_as_uint(x);
    unsigned int r = (u + 0x7fffu + ((u >> 16) & 1u)) >> 16;
    return (unsigned short)r;
}
__device__ __forceinline__ float fast_rcp(float x) { return __builtin_amdgcn_rcpf(x); }
__device__ __forceinline__ float sigmoidf_(float x) { return fast_rcp(1.f + __expf(-x)); }
__device__ __forceinline__ float tanhf_(float x) {
    float e = __expf(2.f * x);
    return 1.f - 2.f * fast_rcp(e + 1.f);
}

// ---- coherent (agent-scope sc1) accessors for cross-WG activation data ----
__device__ __forceinline__ short8 ldA16(const ushort_t* p) {
    ull2 v;
    v.x = __hip_atomic_load((const ull_t*)p, __ATOMIC_RELAXED, __HIP_MEMORY_SCOPE_AGENT);
    v.y = __hip_atomic_load((const ull_t*)p + 1, __ATOMIC_RELAXED, __HIP_MEMORY_SCOPE_AGENT);
    return __builtin_bit_cast(short8, v);
}
__device__ __forceinline__ void stC8(ushort_t* p, ull_t v) {
    __hip_atomic_store((ull_t*)p, v, __ATOMIC_RELAXED, __HIP_MEMORY_SCOPE_AGENT);
}
__device__ __forceinline__ void stC4(ushort_t* p, unsigned int v) {
    __hip_atomic_store((unsigned int*)p, v, __ATOMIC_RELAXED, __HIP_MEMORY_SCOPE_AGENT);
}
__device__ __forceinline__ void stCf(float* p, float v) {
    __hip_atomic_store(p, v, __ATOMIC_RELAXED, __HIP_MEMORY_SCOPE_AGENT);
}
__device__ __forceinline__ float ldCf(const float* p) {
    return __hip_atomic_load(p, __ATOMIC_RELAXED, __HIP_MEMORY_SCOPE_AGENT);
}
// Coherence-point read that the compiler CANNOT turn into a cacheable load:
// a CAS with a never-matching expected value; failed CAS returns the fresh value.
__device__ __forceinline__ int cpoll(int* p) {
    int expected = -2000000000;
    __hip_atomic_compare_exchange_strong(p, &expected, -2000000000, __ATOMIC_RELAXED,
                                         __ATOMIC_RELAXED, __HIP_MEMORY_SCOPE_AGENT);
    return expected;
}

// K-chunked dual-chain GEMM with coherent A loads (register double-buffer).
template <int NK, int CH>
__device__ __forceinline__ void gemm2_sc1(const ushort_t* __restrict__ ap,
                                          const ushort_t* __restrict__ bp0,
                                          const ushort_t* __restrict__ bp1,
                                          floatx4& acc0, floatx4& acc1) {
    static_assert(NK % CH == 0, "");
    constexpr int NCH = NK / CH;
    short8 ab[2][CH];
#pragma unroll
    for (int i = 0; i < CH; ++i) ab[0][i] = ldA16(ap + i * 32);
#pragma unroll
    for (int c = 0; c < NCH; ++c) {
        if (c + 1 < NCH) {
#pragma unroll
            for (int i = 0; i < CH; ++i)
                ab[(c + 1) & 1][i] = ldA16(ap + ((c + 1) * CH + i) * 32);
        }
#pragma unroll
        for (int i = 0; i < CH; ++i) {
            const int ks = c * CH + i;
            short8 b0 = *(const short8*)(bp0 + ks * 32);
            short8 b1 = *(const short8*)(bp1 + ks * 32);
            acc0 = __builtin_amdgcn_mfma_f32_16x16x32_bf16(ab[c & 1][i], b0, acc0, 0, 0, 0);
            acc1 = __builtin_amdgcn_mfma_f32_16x16x32_bf16(ab[c & 1][i], b1, acc1, 0, 0, 0);
        }
    }
}

// ---------------- one-time prep kernels ----------------

__global__ void cvt_kernel(const float* __restrict__ src, ushort_t* __restrict__ dst, int n) {
    int i = blockIdx.x * 256 + threadIdx.x;
    if (i < n) dst[i] = f2bf(src[i]);
}

__global__ void zero_kernel(int* __restrict__ p, int n) {
    int i = blockIdx.x * 256 + threadIdx.x;
    if (i < n) p[i] = 0;
}

__global__ void addv_kernel(const float* __restrict__ a, const float* __restrict__ b,
                            float* __restrict__ o, int n) {
    int i = blockIdx.x * 256 + threadIdx.x;
    if (i < n) o[i] = a[i] + b[i];
}

__global__ void mean_kernel(const float* __restrict__ feat, float* __restrict__ meanv) {
    int idx = blockIdx.x * 256 + threadIdx.x;
    int b = idx >> 10;
    int e = idx & 1023;
    const float* p = feat + (size_t)b * PP * 1024 + e;
    float s = 0.f;
    for (int pp = 0; pp < PP; ++pp) s += p[(size_t)pp * 1024];
    meanv[idx] = s * (1.f / 196.f);
}

__global__ __launch_bounds__(256) void init_kernel(
    const float* __restrict__ meanv, const float* __restrict__ Wh0, const float* __restrict__ bh0,
    const float* __restrict__ Wc0, const float* __restrict__ bc0,
    float* __restrict__ c1, float* __restrict__ c2,
    ushort_t* __restrict__ h1b, ushort_t* __restrict__ h2b) {
    int b = blockIdx.x, t = threadIdx.x;
    __shared__ float ml[1024];
    for (int i = t; i < 1024; i += 256) ml[i] = meanv[b * 1024 + i];
    __syncthreads();
    for (int d = t; d < 512; d += 256) {
        const float4* wh = (const float4*)(Wh0 + (size_t)d * 1024);
        const float4* wc = (const float4*)(Wc0 + (size_t)d * 1024);
        float ah = bh0[d], ac = bc0[d];
        #pragma unroll 4
        for (int j = 0; j < 256; ++j) {
            float4 w = wh[j];
            ah += w.x * ml[4 * j] + w.y * ml[4 * j + 1] + w.z * ml[4 * j + 2] + w.w * ml[4 * j + 3];
        }
        #pragma unroll 4
        for (int j = 0; j < 256; ++j) {
            float4 w = wc[j];
            ac += w.x * ml[4 * j] + w.y * ml[4 * j + 1] + w.z * ml[4 * j + 2] + w.w * ml[4 * j + 3];
        }
        c1[b * 512 + d] = ac;
        c2[b * 512 + d] = ac;
        ushort_t hb = f2bf(ah);
        h1b[b * 512 + d] = hb;
        h2b[b * 512 + d] = hb;
    }
}

__global__ __launch_bounds__(256) void enc_gemm(
    const ushort_t* __restrict__ feat_bf, const ushort_t* __restrict__ wenc_bf,
    const float* __restrict__ benc, ushort_t* __restrict__ enc_bf) {
    const int t = threadIdx.x, blk = blockIdx.x;
    const int bm = (blk % 392) * 64, bn = (blk / 392) * 64;
    const int lane = t & 63, wv = t >> 6;
    const int n = lane & 15, q = lane >> 4;
    const int arow = bm + wv * 16 + n;
    const short8* ap = (const short8*)(feat_bf + (size_t)arow * 1024 + q * 8);
    const short8* bp0 = (const short8*)(wenc_bf + (size_t)(bn + 0 * 16 + n) * 1024 + q * 8);
    const short8* bp1 = (const short8*)(wenc_bf + (size_t)(bn + 1 * 16 + n) * 1024 + q * 8);
    const short8* bp2 = (const short8*)(wenc_bf + (size_t)(bn + 2 * 16 + n) * 1024 + q * 8);
    const short8* bp3 = (const short8*)(wenc_bf + (size_t)(bn + 3 * 16 + n) * 1024 + q * 8);
    floatx4 acc0 = {0.f, 0.f, 0.f, 0.f}, acc1 = acc0, acc2 = acc0, acc3 = acc0;
    for (int ks = 0; ks < 32; ++ks) {
        short8 a8 = ap[ks * 4];
        acc0 = __builtin_amdgcn_mfma_f32_16x16x32_bf16(a8, bp0[ks * 4], acc0, 0, 0, 0);
        acc1 = __builtin_amdgcn_mfma_f32_16x16x32_bf16(a8, bp1[ks * 4], acc1, 0, 0, 0);
        acc2 = __builtin_amdgcn_mfma_f32_16x16x32_bf16(a8, bp2[ks * 4], acc2, 0, 0, 0);
        acc3 = __builtin_amdgcn_mfma_f32_16x16x32_bf16(a8, bp3[ks * 4], acc3, 0, 0, 0);
    }
    #pragma unroll
    for (int r = 0; r < 4; ++r) {
        int m = bm + wv * 16 + q * 4 + r;
        int a0 = bn + n;
        enc_bf[(size_t)m * 512 + a0] = f2bf(acc0[r] + benc[a0]);
        enc_bf[(size_t)m * 512 + a0 + 16] = f2bf(acc1[r] + benc[a0 + 16]);
        enc_bf[(size_t)m * 512 + a0 + 32] = f2bf(acc2[r] + benc[a0 + 32]);
        enc_bf[(size_t)m * 512 + a0 + 48] = f2bf(acc3[r] + benc[a0 + 48]);
    }
}

// ---------------- persistent decode loop (grid = 256, 1 WG/CU) ----------------
// Barrier: arrive = fetch_add RMW (memory-side, always coherent); release flags
// bumped via fetch_add; waiters poll via failing-CAS (cpoll) so reads hit the
// coherence point. One agent-RELEASE fence per barrier (writeback only, no
// invalidate -> L2 stays warm). Timeout poisons the barrier -> kernel always
// terminates (diagnosable failure instead of a dead container).
__device__ __forceinline__ void gbar(int* __restrict__ bar, int k) {
    asm volatile("s_waitcnt vmcnt(0)" ::: "memory");
    __syncthreads();
    if (threadIdx.x == 0) {
        __builtin_amdgcn_fence(__ATOMIC_RELEASE, "agent");
        if (cpoll(bar + 992) == 0) {
            const int g = blockIdx.x >> 5;
            int old = __hip_atomic_fetch_add(bar + g * 32, 1, __ATOMIC_RELAXED,
                                             __HIP_MEMORY_SCOPE_AGENT);
            if (old + 1 == 32 * k) {
                int r = __hip_atomic_fetch_add(bar + 320, 1, __ATOMIC_RELAXED,
                                               __HIP_MEMORY_SCOPE_AGENT);
                if (r + 1 == 8 * k) {
                    #pragma unroll
                    for (int g2 = 0; g2 < 8; ++g2)
                        __hip_atomic_fetch_add(bar + 384 + g2 * 32, 1, __ATOMIC_RELAXED,
                                               __HIP_MEMORY_SCOPE_AGENT);
                }
            }
            int spins = 0;
            while (cpoll(bar + 384 + g * 32) < k) {
                __builtin_amdgcn_s_sleep(1);
                if (++spins > 300000) {  // ~0.1-0.2 s: legit waits are ~µs
                    __hip_atomic_store(bar + 992, 1, __ATOMIC_RELAXED, __HIP_MEMORY_SCOPE_AGENT);
                    break;
                }
            }
        }
    }
    __syncthreads();
}

// preds[s-1] = h2 @ Wf^T + bf; 64 WGs x [64 rows x 32 cols], K=512
__device__ __forceinline__ void preds_tile(int w2, int s, const ushort_t* __restrict__ h2cur,
                                           const ushort_t* __restrict__ wf_bf,
                                           const float* __restrict__ bfv,
                                           float* __restrict__ out, int wv, int n, int q) {
    const int vt = w2 >> 1, mt = w2 & 1;
    const int v0 = vt * 32;
    const int m0 = mt * 64 + wv * 16;
    const int vr0 = v0 + n, vr1 = v0 + 16 + n;
    const int vc0 = vr0 < VV ? vr0 : VV - 1;
    const int vc1 = vr1 < VV ? vr1 : VV - 1;
    floatx4 acc0 = {0.f, 0.f, 0.f, 0.f}, acc1 = acc0;
    gemm2_sc1<16, 8>(h2cur + (size_t)(m0 + n) * 512 + q * 8,
                     wf_bf + (size_t)vc0 * 512 + q * 8,
                     wf_bf + (size_t)vc1 * 512 + q * 8, acc0, acc1);
    const size_t so = (size_t)(s - 1) * 1000;
    #pragma unroll
    for (int r = 0; r < 4; ++r) {
        int br = m0 + q * 4 + r;
        if (vr0 < VV) out[(size_t)br * 256000 + so + vr0] = acc0[r] + bfv[vr0];
        if (vr1 < VV) out[(size_t)br * 256000 + so + vr1] = acc1[r] + bfv[vr1];
    }
}

// LSTM layer phase: 128 WGs, WG = [32 batches x 16 d] x 4 gates.
template <int NK1, int CH1>
__device__ __forceinline__ void lstm_phase(
    int wg, int t, int wv, int n, int q, int K1,
    const ushort_t* __restrict__ A1, const ushort_t* __restrict__ W1,
    const ushort_t* __restrict__ A2v, const ushort_t* __restrict__ W2,
    const float* __restrict__ bsum,
    float& cA, float& cB, ushort_t* __restrict__ hout, float (*glds)[65]) {
    const int mt = wg >> 5, ct = wg & 31, d0 = ct * 16;
    const int rh2 = wv & 1, ch = wv >> 1;
    const int m0 = mt * 32 + rh2 * 16;
    const int g0 = ch * 2, g1 = g0 + 1;
    floatx4 acc0 = {0.f, 0.f, 0.f, 0.f}, acc1 = acc0;
    gemm2_sc1<NK1, CH1>(A1 + (size_t)(m0 + n) * K1 + q * 8,
                        W1 + (size_t)(g0 * 512 + d0 + n) * K1 + q * 8,
                        W1 + (size_t)(g1 * 512 + d0 + n) * K1 + q * 8, acc0, acc1);
    gemm2_sc1<16, 8>(A2v + (size_t)(m0 + n) * 512 + q * 8,
                     W2 + (size_t)(g0 * 512 + d0 + n) * 512 + q * 8,
                     W2 + (size_t)(g1 * 512 + d0 + n) * 512 + q * 8, acc0, acc1);
    #pragma unroll
    for (int r = 0; r < 4; ++r) {
        glds[rh2 * 16 + q * 4 + r][g0 * 16 + n] = acc0[r];
        glds[rh2 * 16 + q * 4 + r][g1 * 16 + n] = acc1[r];
    }
    __syncthreads();
    const int bl = t >> 3, dj = (t & 7) * 2;
    const int b = mt * 32 + bl, d = d0 + dj;
    float gi0 = glds[bl][dj] + bsum[d];
    float gi1 = glds[bl][dj + 1] + bsum[d + 1];
    float gf0 = glds[bl][16 + dj] + bsum[512 + d];
    float gf1 = glds[bl][17 + dj] + bsum[512 + d + 1];
    float gg0 = glds[bl][32 + dj] + bsum[1024 + d];
    float gg1 = glds[bl][33 + dj] + bsum[1024 + d + 1];
    float go0 = glds[bl][48 + dj] + bsum[1536 + d];
    float go1 = glds[bl][49 + dj] + bsum[1536 + d + 1];
    float cn0 = sigmoidf_(gf0) * cA + sigmoidf_(gi0) * tanhf_(gg0);
    float cn1 = sigmoidf_(gf1) * cB + sigmoidf_(gi1) * tanhf_(gg1);
    cA = cn0;
    cB = cn1;
    float hn0 = sigmoidf_(go0) * tanhf_(cn0);
    float hn1 = sigmoidf_(go1) * tanhf_(cn1);
    unsigned int pk = (unsigned int)f2bf(hn0) | ((unsigned int)f2bf(hn1) << 16);
    stC4(hout + (size_t)b * 512 + d, pk);
}

__global__ __launch_bounds__(256, 1) void decode_loop(
    const ushort_t* __restrict__ enc_bf, const ushort_t* __restrict__ feat_bf,
    const ushort_t* __restrict__ wdec_bf, const ushort_t* __restrict__ wf_bf,
    const ushort_t* __restrict__ emb_bf,
    const ushort_t* __restrict__ w1ih_bf, const ushort_t* __restrict__ w1hh_bf,
    const ushort_t* __restrict__ w2ih_bf, const ushort_t* __restrict__ w2hh_bf,
    const int* __restrict__ latexes,
    const float* __restrict__ wattn, const float* __restrict__ battn,
    const float* __restrict__ bdec, const float* __restrict__ bfv,
    const float* __restrict__ b1s, const float* __restrict__ b2s,
    const float* __restrict__ c1i, const float* __restrict__ c2i,
    ushort_t* __restrict__ h1b0, ushort_t* __restrict__ h1b1,
    ushort_t* __restrict__ h2b0, ushort_t* __restrict__ h2b1,
    ushort_t* __restrict__ x1_bf, float* __restrict__ decb, float* __restrict__ alpha_g,
    float* __restrict__ out, int* __restrict__ bar) {
    const int wg = blockIdx.x, t = threadIdx.x;
    const int lane = t & 63, wv = t >> 6;
    const int n = lane & 15, q = lane >> 4;

    __shared__ float wa_lds[512];
    __shared__ float dec_lds[512];
    __shared__ float red[256];
    __shared__ float attn_lds[200];
    __shared__ float alpha_lds[200];
    __shared__ float glds[32][65];

    float c1A = 0.f, c1B = 0.f, c2A = 0.f, c2B = 0.f;
    if (wg < 128) {
        const int mt = wg >> 5, ct = wg & 31;
        const int b = mt * 32 + (t >> 3), d = ct * 16 + (t & 7) * 2;
        c1A = c1i[b * 512 + d];
        c1B = c1i[b * 512 + d + 1];
        c2A = c2i[b * 512 + d];
        c2B = c2i[b * 512 + d + 1];
        for (int i = t; i < 512; i += 256) wa_lds[i] = wattn[i];
    }

    int bc = 0;
    for (int s = 0;; ++s) {
        const ushort_t* h1cur = (s & 1) ? h1b1 : h1b0;
        const ushort_t* h2cur = (s & 1) ? h2b1 : h2b0;
        ushort_t* h1nxt = (s & 1) ? h1b0 : h1b1;
        ushort_t* h2nxt = (s & 1) ? h2b0 : h2b1;

        if (s == SS) {  // final vocab projection, then everyone exits
            if (wg >= 128 && wg < 192) preds_tile(wg - 128, SS, h2cur, wf_bf, bfv, out, wv, n, q);
            break;
        }

        // ---- P1: dec_t = h2 @ Wdec^T + bdec  (32 WGs x [64 x 32], K=512) ----
        if (wg < 32) {
            const int nt = wg >> 1, mh = wg & 1;
            const int n0 = nt * 32;
            const int m0 = mh * 64 + wv * 16;
            floatx4 acc0 = {0.f, 0.f, 0.f, 0.f}, acc1 = acc0;
            gemm2_sc1<16, 8>(h2cur + (size_t)(m0 + n) * 512 + q * 8,
                             wdec_bf + (size_t)(n0 + n) * 512 + q * 8,
                             wdec_bf + (size_t)(n0 + 16 + n) * 512 + q * 8, acc0, acc1);
            const float cb0 = bdec[n0 + n], cb1 = bdec[n0 + 16 + n];
            #pragma unroll
            for (int r = 0; r < 4; ++r) {
                stCf(decb + (size_t)(m0 + q * 4 + r) * 512 + n0 + n, acc0[r] + cb0);
                stCf(decb + (size_t)(m0 + q * 4 + r) * 512 + n0 + 16 + n, acc1[r] + cb1);
            }
        }
        gbar(bar, ++bc);

        // ---- P2: logits + softmax (WG 0..127, b = wg) ----
        if (wg < BB) {
            const int b = wg;
            if (t < 32) {
                int tok = latexes[b * 257 + s];
                ull_t v = *(const ull_t*)(emb_bf + (size_t)tok * TT + t * 4);
                stC8(x1_bf + (size_t)b * 1152 + t * 4, v);
            }
            for (int i = t; i < 512; i += 256) dec_lds[i] = ldCf(decb + b * 512 + i);
            __syncthreads();
            for (int p = wv; p < PP; p += 4) {
                const ushort8_t ev =
                    *(const ushort8_t*)(enc_bf + ((size_t)(b * PP + p)) * 512 + lane * 8);
                float acc = 0.f;
                #pragma unroll
                for (int u = 0; u < 8; ++u) {
                    float x = bf2f(ev[u]) + dec_lds[lane * 8 + u];
                    acc += wa_lds[lane * 8 + u] * tanhf_(x);
                }
                #pragma unroll
                for (int off = 32; off > 0; off >>= 1) acc += __shfl_xor(acc, off, 64);
                if (lane == 0) attn_lds[p] = acc + battn[0];
            }
            __syncthreads();
            float logit = (t < PP) ? attn_lds[t] : -1e30f;
            red[t] = logit;
            __syncthreads();
            for (int st = 128; st > 0; st >>= 1) {
                if (t < st) red[t] = fmaxf(red[t], red[t + st]);
                __syncthreads();
            }
            float mx = red[0];
            __syncthreads();
            float e = (t < PP) ? __expf(logit - mx) : 0.f;
            red[t] = e;
            __syncthreads();
            for (int st = 128; st > 0; st >>= 1) {
                if (t < st) red[t] += red[t + st];
                __syncthreads();
            }
            float inv = fast_rcp(red[0]);
            if (t < PP) {
                float a = e * inv;
                stCf(alpha_g + b * 256 + t, a);
                out[(size_t)32768000 + (size_t)b * 50176 + (size_t)s * 196 + t] = a;
            }
        }
        gbar(bar, ++bc);

        // ---- P3: awe (all 256 WGs; each covers half the e-range of one batch) ----
        {
            const int b3 = wg & 127, ebase = (wg >> 7) * 512;
            if (t < PP) alpha_lds[t] = ldCf(alpha_g + b3 * 256 + t);
            __syncthreads();
            const int e = ebase + t * 2;
            const ushort_t* fb = feat_bf + (size_t)b3 * PP * 1024 + e;
            float a0 = 0.f, a1 = 0.f;
            #pragma unroll 4
            for (int p = 0; p < PP; ++p) {
                unsigned int fv = *(const unsigned int*)(fb + (size_t)p * 1024);
                float av = alpha_lds[p];
                a0 += av * bf2f((unsigned short)(fv & 0xffffu));
                a1 += av * bf2f((unsigned short)(fv >> 16));
            }
            unsigned int pk = (unsigned int)f2bf(a0) | ((unsigned int)f2bf(a1) << 16);
            stC4(x1_bf + (size_t)b3 * 1152 + TT + e, pk);
        }
        gbar(bar, ++bc);

        // ---- P4: lstm1 (WG 0..127) || preds[s-1] (WG 128..191) ----
        if (wg < 128) {
            lstm_phase<36, 9>(wg, t, wv, n, q, 1152, x1_bf, w1ih_bf, h1cur, w1hh_bf,
                              b1s, c1A, c1B, h1nxt, glds);
        } else if (wg < 192 && s > 0) {
            preds_tile(wg - 128, s, h2cur, wf_bf, bfv, out, wv, n, q);
        }
        gbar(bar, ++bc);

        // ---- P5: lstm2 (WG 0..127) ----
        if (wg < 128)
            lstm_phase<16, 8>(wg, t, wv, n, q, 512, h1nxt, w2ih_bf, h2cur, w2hh_bf,
                              b2s, c2A, c2B, h2nxt, glds);
        gbar(bar, ++bc);
    }
}

extern "C" void kernel_launch(void* const* d_in, const int* in_sizes, int n_in,
                              void* d_out, int out_size, void* d_ws, size_t ws_size,
                              hipStream_t stream) {
    const float* features = (const float*)d_in[0];
    const int* latexes = (const int*)d_in[1];
    const float* emb = (const float*)d_in[2];
    const float* Wenc = (const float*)d_in[3];
    const float* benc = (const float*)d_in[4];
    const float* Wdec = (const float*)d_in[5];
    const float* bdec = (const float*)d_in[6];
    const float* Wattn = (const float*)d_in[7];
    const float* battn = (const float*)d_in[8];
    const float* W1ih = (const float*)d_in[9];
    const float* W1hh = (const float*)d_in[10];
    const float* b1ih = (const float*)d_in[11];
    const float* b1hh = (const float*)d_in[12];
    const float* W2ih = (const float*)d_in[13];
    const float* W2hh = (const float*)d_in[14];
    const float* b2ih = (const float*)d_in[15];
    const float* b2hh = (const float*)d_in[16];
    const float* Wh0 = (const float*)d_in[17];
    const float* bh0 = (const float*)d_in[18];
    const float* Wc0 = (const float*)d_in[19];
    const float* bc0 = (const float*)d_in[20];
    const float* Wf = (const float*)d_in[23];
    const float* bfv = (const float*)d_in[24];
    float* out = (float*)d_out;

    char* ws = (char*)d_ws;
    size_t off = 0;
    auto alloc = [&](size_t bytes) {
        void* p = ws + off;
        off += (bytes + 255) & ~(size_t)255;
        return p;
    };
    ushort_t* feat_bf = (ushort_t*)alloc(25690112ull * 2);
    ushort_t* enc_bf = (ushort_t*)alloc(12845056ull * 2);
    ushort_t* w1ih_bf = (ushort_t*)alloc(2359296ull * 2);
    ushort_t* w1hh_bf = (ushort_t*)alloc(1048576ull * 2);
    ushort_t* w2ih_bf = (ushort_t*)alloc(1048576ull * 2);
    ushort_t* w2hh_bf = (ushort_t*)alloc(1048576ull * 2);
    ushort_t* wf_bf = (ushort_t*)alloc(512000ull * 2);
    ushort_t* wdec_bf = (ushort_t*)alloc(262144ull * 2);
    ushort_t* wenc_bf = (ushort_t*)alloc(524288ull * 2);
    ushort_t* emb_bf = (ushort_t*)alloc(128000ull * 2);
    float* meanv = (float*)alloc(131072ull * 4);
    float* c1 = (float*)alloc(65536ull * 4);
    float* c2 = (float*)alloc(65536ull * 4);
    ushort_t* h1b0 = (ushort_t*)alloc(65536ull * 2);
    ushort_t* h1b1 = (ushort_t*)alloc(65536ull * 2);
    ushort_t* h2b0 = (ushort_t*)alloc(65536ull * 2);
    ushort_t* h2b1 = (ushort_t*)alloc(65536ull * 2);
    ushort_t* x1_bf = (ushort_t*)alloc(147456ull * 2);
    float* decb = (float*)alloc(65536ull * 4);
    float* alpha_g = (float*)alloc(32768ull * 4);
    float* b1s = (float*)alloc(2048ull * 4);
    float* b2s = (float*)alloc(2048ull * 4);
    int* bar = (int*)alloc(1024 * sizeof(int));

    auto cv = [&](const float* s, ushort_t* d, int n) {
        cvt_kernel<<<(n + 255) / 256, 256, 0, stream>>>(s, d, n);
    };
    cv(features, feat_bf, 25690112);
    cv(Wenc, wenc_bf, 524288);
    cv(W1ih, w1ih_bf, 2359296);
    cv(W1hh, w1hh_bf, 1048576);
    cv(W2ih, w2ih_bf, 1048576);
    cv(W2hh, w2hh_bf, 1048576);
    cv(Wf, wf_bf, 512000);
    cv(Wdec, wdec_bf, 262144);
    cv(emb, emb_bf, 128000);
    zero_kernel<<<4, 256, 0, stream>>>(bar, 1024);
    addv_kernel<<<8, 256, 0, stream>>>(b1ih, b1hh, b1s, 2048);
    addv_kernel<<<8, 256, 0, stream>>>(b2ih, b2hh, b2s, 2048);
    mean_kernel<<<512, 256, 0, stream>>>(features, meanv);
    init_kernel<<<128, 256, 0, stream>>>(meanv, Wh0, bh0, Wc0, bc0, c1, c2, h1b0, h2b0);
    enc_gemm<<<3136, 256, 0, stream>>>(feat_bf, wenc_bf, benc, enc_bf);

    decode_loop<<<256, 256, 0, stream>>>(
        enc_bf, feat_bf, wdec_bf, wf_bf, emb_bf, w1ih_bf, w1hh_bf, w2ih_bf, w2hh_bf,
        latexes, Wattn, battn, bdec, bfv, b1s, b2s, c1, c2,
        h1b0, h1b1, h2b0, h2b1, x1_bf, decb, alpha_g, out, bar);
}